// Round 1
// baseline (314.789 us; speedup 1.0000x reference)
//
#include <hip/hip_runtime.h>
#include <stdint.h>

#define NS 32
#define NIN 2048
#define NOUT 2048

// ---------- Threefry-2x32 (20 rounds), exact JAX semantics ----------
#define TF_ROUND(x0, x1, r)                       \
    do {                                          \
        x0 += x1;                                 \
        x1 = (x1 << (r)) | (x1 >> (32 - (r)));    \
        x1 ^= x0;                                 \
    } while (0)

__device__ __forceinline__ uint2 tf2x32_dev(uint32_t k0, uint32_t k1,
                                            uint32_t x0, uint32_t x1) {
    uint32_t k2 = k0 ^ k1 ^ 0x1BD11BDAu;
    x0 += k0; x1 += k1;
    TF_ROUND(x0, x1, 13); TF_ROUND(x0, x1, 15); TF_ROUND(x0, x1, 26); TF_ROUND(x0, x1, 6);
    x0 += k1; x1 += k2 + 1u;
    TF_ROUND(x0, x1, 17); TF_ROUND(x0, x1, 29); TF_ROUND(x0, x1, 16); TF_ROUND(x0, x1, 24);
    x0 += k2; x1 += k0 + 2u;
    TF_ROUND(x0, x1, 13); TF_ROUND(x0, x1, 15); TF_ROUND(x0, x1, 26); TF_ROUND(x0, x1, 6);
    x0 += k0; x1 += k1 + 3u;
    TF_ROUND(x0, x1, 17); TF_ROUND(x0, x1, 29); TF_ROUND(x0, x1, 16); TF_ROUND(x0, x1, 24);
    x0 += k1; x1 += k2 + 4u;
    TF_ROUND(x0, x1, 13); TF_ROUND(x0, x1, 15); TF_ROUND(x0, x1, 26); TF_ROUND(x0, x1, 6);
    x0 += k2; x1 += k0 + 5u;
    return make_uint2(x0, x1);
}

// partitionable random_bits (32-bit): hash of (key, 0, flat_index), fold halves
__device__ __forceinline__ uint32_t jax_bits32(uint32_t k0, uint32_t k1, uint32_t p) {
    uint2 y = tf2x32_dev(k0, k1, 0u, p);
    return y.x ^ y.y;
}

// bits -> uniform(-1+2^-24, 1) -> sqrt(2)*erfinv (XLA/Giles polynomial)
__device__ __forceinline__ float normal_from_bits(uint32_t bits) {
    const float LO = __uint_as_float(0xBF7FFFFFu);  // nextafter(-1.f, 0.f)
    float f = __uint_as_float((bits >> 9) | 0x3f800000u) - 1.0f;  // [0,1)
    float u = fmaxf(LO, fmaf(f, 2.0f, LO));  // (maxval-minval) rounds to 2.0f in f32
    float w = -__logf(fmaf(-u, u, 1.0f));    // -log1p(-u*u), single-rounded 1-u^2
    float p;
    if (w < 5.0f) {
        w -= 2.5f;
        p = 2.81022636e-08f;
        p = fmaf(p, w, 3.43273939e-07f);
        p = fmaf(p, w, -3.5233877e-06f);
        p = fmaf(p, w, -4.39150654e-06f);
        p = fmaf(p, w, 0.00021858087f);
        p = fmaf(p, w, -0.00125372503f);
        p = fmaf(p, w, -0.00417768164f);
        p = fmaf(p, w, 0.246640727f);
        p = fmaf(p, w, 1.50140941f);
    } else {
        w = __fsqrt_rn(w) - 3.0f;
        p = -0.000200214257f;
        p = fmaf(p, w, 0.000100950558f);
        p = fmaf(p, w, 0.00134934322f);
        p = fmaf(p, w, -0.00367342844f);
        p = fmaf(p, w, 0.00573950773f);
        p = fmaf(p, w, -0.0076224613f);
        p = fmaf(p, w, 0.00943887047f);
        p = fmaf(p, w, 1.00167406f);
        p = fmaf(p, w, 2.83297682f);
    }
    return 1.41421356237f * p * u;  // sqrt(2) * erfinv(u)
}

__global__ __launch_bounds__(256, 2) void bayes_linear_kernel(
    const float* __restrict__ x, const float* __restrict__ wmu,
    const float* __restrict__ wsg, const float* __restrict__ bmu,
    const float* __restrict__ bsg, float* __restrict__ out,
    uint32_t kw0, uint32_t kw1, uint32_t kb0, uint32_t kb1) {
    const int o = blockIdx.x;
    const int tid = threadIdx.x;

    float acc[NS];
#pragma unroll
    for (int s = 0; s < NS; ++s) acc[s] = 0.0f;

    const uint32_t baseo = (uint32_t)o * NIN;

    for (int j = 0; j < NIN; j += 256) {
        const int i = j + tid;
        const float mu = wmu[baseo + (uint32_t)i];
        const float sg = wsg[baseo + (uint32_t)i];
        const uint32_t pbase = baseo + (uint32_t)i;  // o*IN + i
#pragma unroll 8
        for (int s = 0; s < NS; ++s) {
            // flat index into (S, OUT, IN): s*OUT*IN + o*IN + i  (< 2^27, hi word 0)
            const uint32_t p = pbase + (uint32_t)s * (uint32_t)(NOUT * NIN);
            const float e = normal_from_bits(jax_bits32(kw0, kw1, p));
            const float xs = x[s * NIN + i];
            acc[s] = fmaf(fmaf(sg, e, mu), xs, acc[s]);
        }
    }

    // ---- reduction: 64-lane shuffle per accumulator, then combine 4 waves via LDS ----
    __shared__ float red[4][NS];
    const int lane = tid & 63;
    const int wv = tid >> 6;
#pragma unroll
    for (int s = 0; s < NS; ++s) {
        float v = acc[s];
        v += __shfl_down(v, 32, 64);
        v += __shfl_down(v, 16, 64);
        v += __shfl_down(v, 8, 64);
        v += __shfl_down(v, 4, 64);
        v += __shfl_down(v, 2, 64);
        v += __shfl_down(v, 1, 64);
        if (lane == 0) red[wv][s] = v;
    }
    __syncthreads();

    if (tid < NS) {
        const int s = tid;
        float sum = red[0][s] + red[1][s] + red[2][s] + red[3][s];
        // bias eps: flat index into (S, OUT): s*OUT + o
        const uint32_t pb = (uint32_t)(s * NOUT + o);
        const float eb = normal_from_bits(jax_bits32(kb0, kb1, pb));
        out[s * NOUT + o] = sum + fmaf(bsg[o], eb, bmu[o]);
    }
}

// ---------- host-side threefry for key derivation ----------
static void tf2x32_host(uint32_t k0, uint32_t k1, uint32_t x0, uint32_t x1,
                        uint32_t* y0, uint32_t* y1) {
    uint32_t k2 = k0 ^ k1 ^ 0x1BD11BDAu;
    x0 += k0; x1 += k1;
    TF_ROUND(x0, x1, 13); TF_ROUND(x0, x1, 15); TF_ROUND(x0, x1, 26); TF_ROUND(x0, x1, 6);
    x0 += k1; x1 += k2 + 1u;
    TF_ROUND(x0, x1, 17); TF_ROUND(x0, x1, 29); TF_ROUND(x0, x1, 16); TF_ROUND(x0, x1, 24);
    x0 += k2; x1 += k0 + 2u;
    TF_ROUND(x0, x1, 13); TF_ROUND(x0, x1, 15); TF_ROUND(x0, x1, 26); TF_ROUND(x0, x1, 6);
    x0 += k0; x1 += k1 + 3u;
    TF_ROUND(x0, x1, 17); TF_ROUND(x0, x1, 29); TF_ROUND(x0, x1, 16); TF_ROUND(x0, x1, 24);
    x0 += k1; x1 += k2 + 4u;
    TF_ROUND(x0, x1, 13); TF_ROUND(x0, x1, 15); TF_ROUND(x0, x1, 26); TF_ROUND(x0, x1, 6);
    x0 += k2; x1 += k0 + 5u;
    *y0 = x0; *y1 = x1;
}

extern "C" void kernel_launch(void* const* d_in, const int* in_sizes, int n_in,
                              void* d_out, int out_size, void* d_ws, size_t ws_size,
                              hipStream_t stream) {
    const float* x   = (const float*)d_in[0];
    const float* wmu = (const float*)d_in[1];
    const float* wsg = (const float*)d_in[2];
    const float* bmu = (const float*)d_in[3];
    const float* bsg = (const float*)d_in[4];
    float* out = (float*)d_out;

    // jax.random.key(42) -> key data (0, 42).
    // split (fold-like, partitionable default): subkey j = full threefry hash of index j.
    uint32_t kw0, kw1, kb0, kb1;
    tf2x32_host(0u, 42u, 0u, 0u, &kw0, &kw1);  // wkey
    tf2x32_host(0u, 42u, 0u, 1u, &kb0, &kb1);  // bkey

    bayes_linear_kernel<<<NOUT, 256, 0, stream>>>(x, wmu, wsg, bmu, bsg, out,
                                                  kw0, kw1, kb0, kb1);
}

// Round 2
// 312.245 us; speedup vs baseline: 1.0081x; 1.0081x over previous
//
#include <hip/hip_runtime.h>
#include <stdint.h>

#define NS 32
#define NIN 2048
#define NOUT 2048

// ---------- Threefry-2x32 (20 rounds), exact JAX semantics ----------
// Force single-instruction rotate: v_alignbit_b32(v,v,32-r) == rotl(v,r)
__device__ __forceinline__ uint32_t rotl32(uint32_t v, uint32_t r) {
    return __builtin_amdgcn_alignbit(v, v, 32u - r);
}

#define TF_R(x0, x1, r)          \
    do {                         \
        x0 += x1;                \
        x1 = rotl32(x1, r) ^ x0; \
    } while (0)

// x1in = counter + k1 (pre-added); x0 starts at 0 so x0+k0 = k0.
// Injection constants (k2+1, k0+2, ...) are wave-uniform -> SGPR-hoisted.
__device__ __forceinline__ uint32_t tf_fold(uint32_t k0, uint32_t k1, uint32_t k2,
                                            uint32_t x1in) {
    uint32_t x0 = k0 + x1in;            // round 1 add, x0 preloaded with k0
    uint32_t x1 = rotl32(x1in, 13) ^ x0;
    TF_R(x0, x1, 15); TF_R(x0, x1, 26); TF_R(x0, x1, 6);
    x0 += k1; x1 += k2 + 1u;
    TF_R(x0, x1, 17); TF_R(x0, x1, 29); TF_R(x0, x1, 16); TF_R(x0, x1, 24);
    x0 += k2; x1 += k0 + 2u;
    TF_R(x0, x1, 13); TF_R(x0, x1, 15); TF_R(x0, x1, 26); TF_R(x0, x1, 6);
    x0 += k0; x1 += k1 + 3u;
    TF_R(x0, x1, 17); TF_R(x0, x1, 29); TF_R(x0, x1, 16); TF_R(x0, x1, 24);
    x0 += k1; x1 += k2 + 4u;
    TF_R(x0, x1, 13); TF_R(x0, x1, 15); TF_R(x0, x1, 26); TF_R(x0, x1, 6);
    x0 += k2; x1 += k0 + 5u;
    return x0 ^ x1;
}

// bits -> uniform(-1+2^-24, 1) -> sqrt(2)*erfinv (XLA/Giles polynomial)
__device__ __forceinline__ float normal_from_bits(uint32_t bits) {
    const float LO = __uint_as_float(0xBF7FFFFFu);  // nextafter(-1.f, 0.f)
    float f = __uint_as_float((bits >> 9) | 0x3f800000u) - 1.0f;  // [0,1)
    float u = fmaf(f, 2.0f, LO);             // f>=0 => u>=LO; fmax(LO,.) is identity
    float w = -__logf(fmaf(-u, u, 1.0f));    // -log1p(-u*u)
    float p;
    if (w < 5.0f) {
        w -= 2.5f;
        p = 2.81022636e-08f;
        p = fmaf(p, w, 3.43273939e-07f);
        p = fmaf(p, w, -3.5233877e-06f);
        p = fmaf(p, w, -4.39150654e-06f);
        p = fmaf(p, w, 0.00021858087f);
        p = fmaf(p, w, -0.00125372503f);
        p = fmaf(p, w, -0.00417768164f);
        p = fmaf(p, w, 0.246640727f);
        p = fmaf(p, w, 1.50140941f);
    } else {
        w = __fsqrt_rn(w) - 3.0f;
        p = -0.000200214257f;
        p = fmaf(p, w, 0.000100950558f);
        p = fmaf(p, w, 0.00134934322f);
        p = fmaf(p, w, -0.00367342844f);
        p = fmaf(p, w, 0.00573950773f);
        p = fmaf(p, w, -0.0076224613f);
        p = fmaf(p, w, 0.00943887047f);
        p = fmaf(p, w, 1.00167406f);
        p = fmaf(p, w, 2.83297682f);
    }
    return 1.41421356237f * p * u;  // sqrt(2) * erfinv(u)
}

__global__ __launch_bounds__(256, 2) void bayes_linear_kernel(
    const float* __restrict__ x, const float* __restrict__ wmu,
    const float* __restrict__ wsg, const float* __restrict__ bmu,
    const float* __restrict__ bsg, float* __restrict__ out,
    uint32_t kw0, uint32_t kw1, uint32_t kb0, uint32_t kb1) {
    const int o = blockIdx.x;
    const int tid = threadIdx.x;

    const uint32_t kw2 = kw0 ^ kw1 ^ 0x1BD11BDAu;  // uniform -> SGPR
    const uint32_t kb2 = kb0 ^ kb1 ^ 0x1BD11BDAu;

    float acc[NS];
#pragma unroll
    for (int s = 0; s < NS; ++s) acc[s] = 0.0f;

    const uint32_t baseo = (uint32_t)o * NIN;

    for (int j = 0; j < NIN; j += 256) {
        const int i = j + tid;
        const float mu = wmu[baseo + (uint32_t)i];
        const float sg = wsg[baseo + (uint32_t)i];
        // counter p = s*OUT*IN + o*IN + i; pre-add k1 once (threefry x1 += k1)
        const uint32_t pbk = baseo + (uint32_t)i + kw1;
#pragma unroll 8
        for (int s = 0; s < NS; ++s) {
            const uint32_t x1in = pbk + (uint32_t)s * (uint32_t)(NOUT * NIN);
            const float e = normal_from_bits(tf_fold(kw0, kw1, kw2, x1in));
            const float xs = x[s * NIN + i];
            acc[s] = fmaf(fmaf(sg, e, mu), xs, acc[s]);
        }
    }

    // ---- reduction: 64-lane shuffle per accumulator, then combine 4 waves via LDS ----
    __shared__ float red[4][NS];
    const int lane = tid & 63;
    const int wv = tid >> 6;
#pragma unroll
    for (int s = 0; s < NS; ++s) {
        float v = acc[s];
        v += __shfl_down(v, 32, 64);
        v += __shfl_down(v, 16, 64);
        v += __shfl_down(v, 8, 64);
        v += __shfl_down(v, 4, 64);
        v += __shfl_down(v, 2, 64);
        v += __shfl_down(v, 1, 64);
        if (lane == 0) red[wv][s] = v;
    }
    __syncthreads();

    if (tid < NS) {
        const int s = tid;
        float sum = red[0][s] + red[1][s] + red[2][s] + red[3][s];
        // bias eps: flat index into (S, OUT): s*OUT + o
        const uint32_t pb = (uint32_t)(s * NOUT + o) + kb1;
        const float eb = normal_from_bits(tf_fold(kb0, kb1, kb2, pb));
        out[s * NOUT + o] = sum + fmaf(bsg[o], eb, bmu[o]);
    }
}

// ---------- host-side threefry for key derivation ----------
#define TF_ROUND_H(x0, x1, r)                     \
    do {                                          \
        x0 += x1;                                 \
        x1 = (x1 << (r)) | (x1 >> (32 - (r)));    \
        x1 ^= x0;                                 \
    } while (0)

static void tf2x32_host(uint32_t k0, uint32_t k1, uint32_t x0, uint32_t x1,
                        uint32_t* y0, uint32_t* y1) {
    uint32_t k2 = k0 ^ k1 ^ 0x1BD11BDAu;
    x0 += k0; x1 += k1;
    TF_ROUND_H(x0, x1, 13); TF_ROUND_H(x0, x1, 15); TF_ROUND_H(x0, x1, 26); TF_ROUND_H(x0, x1, 6);
    x0 += k1; x1 += k2 + 1u;
    TF_ROUND_H(x0, x1, 17); TF_ROUND_H(x0, x1, 29); TF_ROUND_H(x0, x1, 16); TF_ROUND_H(x0, x1, 24);
    x0 += k2; x1 += k0 + 2u;
    TF_ROUND_H(x0, x1, 13); TF_ROUND_H(x0, x1, 15); TF_ROUND_H(x0, x1, 26); TF_ROUND_H(x0, x1, 6);
    x0 += k0; x1 += k1 + 3u;
    TF_ROUND_H(x0, x1, 17); TF_ROUND_H(x0, x1, 29); TF_ROUND_H(x0, x1, 16); TF_ROUND_H(x0, x1, 24);
    x0 += k1; x1 += k2 + 4u;
    TF_ROUND_H(x0, x1, 13); TF_ROUND_H(x0, x1, 15); TF_ROUND_H(x0, x1, 26); TF_ROUND_H(x0, x1, 6);
    x0 += k2; x1 += k0 + 5u;
    *y0 = x0; *y1 = x1;
}

extern "C" void kernel_launch(void* const* d_in, const int* in_sizes, int n_in,
                              void* d_out, int out_size, void* d_ws, size_t ws_size,
                              hipStream_t stream) {
    const float* x   = (const float*)d_in[0];
    const float* wmu = (const float*)d_in[1];
    const float* wsg = (const float*)d_in[2];
    const float* bmu = (const float*)d_in[3];
    const float* bsg = (const float*)d_in[4];
    float* out = (float*)d_out;

    // jax.random.key(42) -> key data (0, 42).
    // split (fold-like, partitionable default): subkey j = full threefry hash of index j.
    uint32_t kw0, kw1, kb0, kb1;
    tf2x32_host(0u, 42u, 0u, 0u, &kw0, &kw1);  // wkey
    tf2x32_host(0u, 42u, 0u, 1u, &kb0, &kb1);  // bkey

    bayes_linear_kernel<<<NOUT, 256, 0, stream>>>(x, wmu, wsg, bmu, bsg, out,
                                                  kw0, kw1, kb0, kb1);
}